// Round 7
// baseline (138.631 us; speedup 1.0000x reference)
//
#include <hip/hip_runtime.h>
#include <hip/hip_fp16.h>
#include <stdint.h>

// SoftmaxSelfAttention: B=2 H=16 S=2048 D=64, fp32 in/out.
// R7: in-block split-K. 512-thread blocks = two 4-wave teams; team t does
// kv-half t for the same 128 q-rows (2 q-strips/wave kept). Each team has
// its own double-buffered 64-kv LDS pipeline (66 KB total -> 2 blocks/CU,
// 16 waves/CU vs R6's 8). Fixed-C exp-domain partials merge through LDS at
// the end (no extra kernel, no extra global traffic).

#define S_LEN   2048
#define DHEAD   64
#define NPER    16                      // periods per team (64 kv each)
#define CEXP    9.0f
#define SCL2E   0.18033688011112042f    // (1/sqrt(64)) * log2(e)
#define L2E     1.4426950408889634f

typedef __attribute__((ext_vector_type(4))) float    f32x4;
typedef __attribute__((ext_vector_type(2))) _Float16 f16x2;
typedef __attribute__((ext_vector_type(4))) _Float16 f16x4;
typedef __attribute__((ext_vector_type(8))) _Float16 f16x8;
typedef __attribute__((ext_vector_type(2))) __fp16   hf16x2;

static __device__ __forceinline__ float exp2_fast(float x) {
#if __has_builtin(__builtin_amdgcn_exp2f)
  return __builtin_amdgcn_exp2f(x);
#else
  float r;
  asm("v_exp_f32 %0, %1" : "=v"(r) : "v"(x));
  return r;
#endif
}

static __device__ __forceinline__ hf16x2 pkh(float a, float b) {
  return __builtin_amdgcn_cvt_pkrtz(a, b);
}
static __device__ __forceinline__ f16x2 h2f(hf16x2 h) {
  union { hf16x2 i; f16x2 o; } u; u.i = h; return u.o;
}

#define GLDS16(g, l)                                                  \
  __builtin_amdgcn_global_load_lds(                                   \
      (const __attribute__((address_space(1))) void*)(g),             \
      (__attribute__((address_space(3))) void*)(l), 16, 0, 0)

// ---------------------------------------------------------------- prep ----
// Blocks [0,2048): K image, chunk c (8 f16) of row kv at rotated pos
// (c+kv)&7; also madd_g[b][kv]. Blocks [2048,6144): V image, granule-major:
// granule (bh,j,g,d) = {V[64j+4g+i][d], i=0..3} at flat (bh<<15|j<<10|g<<6|d).
__global__ __launch_bounds__(256) void prep(
    const float* __restrict__ K, const float* __restrict__ V,
    const float* __restrict__ Mk, _Float16* __restrict__ Kswz,
    _Float16* __restrict__ Vg, float* __restrict__ madd_g) {
  const int gb = blockIdx.x;
  if (gb < 2048) {
    const int idx = gb * 256 + threadIdx.x;   // bh<<14 | kv<<3 | c
    const int c  = idx & 7;
    const int kv = (idx >> 3) & 2047;
    const int bh = idx >> 14;
    const float* src = K + ((size_t)bh * S_LEN + kv) * DHEAD + c * 8;
    float4 a = *(const float4*)(src);
    float4 d = *(const float4*)(src + 4);
    union { f16x2 h[4]; f16x8 v; } r;
    r.h[0] = h2f(pkh(a.x, a.y)); r.h[1] = h2f(pkh(a.z, a.w));
    r.h[2] = h2f(pkh(d.x, d.y)); r.h[3] = h2f(pkh(d.z, d.w));
    *(f16x8*)(Kswz + ((size_t)bh * S_LEN + kv) * DHEAD + ((c + kv) & 7) * 8) = r.v;
    if (idx < 2 * S_LEN)
      madd_g[idx] = -CEXP - (1.0e6f * L2E) * (1.0f - Mk[idx]);
  } else {
    const int idx = (gb - 2048) * 256 + threadIdx.x;  // bh<<15 | j<<10 | g<<6 | d
    const int d  = idx & 63;
    const int g  = (idx >> 6) & 15;
    const int j  = (idx >> 10) & 31;
    const int bh = idx >> 15;
    const float* src = V + ((size_t)bh * S_LEN + j * 64 + g * 4) * DHEAD + d;
    float v0 = src[0], v1 = src[64], v2 = src[128], v3 = src[192];
    union { f16x2 h[2]; f16x4 v; } r;
    r.h[0] = h2f(pkh(v0, v1)); r.h[1] = h2f(pkh(v2, v3));
    *(f16x4*)(Vg + (size_t)idx * 4) = r.v;
  }
}

// ---------------------------------------------------------------- main ----
__global__ __launch_bounds__(512, 4) void attn_ws(
    const float* __restrict__ Q, const _Float16* __restrict__ Kswz,
    const _Float16* __restrict__ Vg, const float* __restrict__ madd_g,
    float* __restrict__ O) {
  // [team][buf][tile]: K 8 KB + V 8 KB per 64-kv tile, per team.
  __shared__ __align__(16) _Float16 kls[2][2][4096];
  __shared__ __align__(16) _Float16 vls[2][2][4096];
  __shared__ __align__(16) float    mls[2][2][64];

  const int tid  = threadIdx.x;
  const int lane = tid & 63;
  const int wave = tid >> 6;      // 0..7
  const int team = wave >> 2;     // 0,1 : kv-half
  const int twav = wave & 3;      // 0..3 within team
  const int ttid = tid & 255;     // 0..255 within team
  const int quad = lane >> 4;
  const int x    = lane & 15;

  // grid 512: 16 q-blocks (128 rows) x 32 bh; same-bh blocks share an XCD.
  const int blk  = blockIdx.x;
  const int bh   = (blk & 7) | (((blk >> 3) & 3) << 3);
  const int qblk = blk >> 5;          // 0..15
  const int b    = bh >> 4;

  const size_t base = (size_t)bh * S_LEN * DHEAD;
  const float*    Qb = Q + base;
  const _Float16* Kb = Kswz + base;
  const _Float16* Vb = Vg + base;
  const float*    Mb = madd_g + b * S_LEN;
  float* Ob = O + base;

  // Q fragments (B-operand of S^T = K Q^T) for two q-strips, pre-scaled.
  const int q0 = qblk * 128 + twav * 16 + x;
  f16x8 qf[2][2];
#pragma unroll
  for (int u = 0; u < 2; ++u) {
    const float* qp = Qb + (size_t)(q0 + u * 64) * DHEAD + quad * 8;
#pragma unroll
    for (int kb = 0; kb < 2; ++kb) {
      float4 a = *(const float4*)(qp + kb * 32);
      float4 c = *(const float4*)(qp + kb * 32 + 4);
      union { f16x2 h[4]; f16x8 v; } r;
      r.h[0] = h2f(pkh(a.x * SCL2E, a.y * SCL2E));
      r.h[1] = h2f(pkh(a.z * SCL2E, a.w * SCL2E));
      r.h[2] = h2f(pkh(c.x * SCL2E, c.y * SCL2E));
      r.h[3] = h2f(pkh(c.z * SCL2E, c.w * SCL2E));
      qf[u][kb] = r.v;
    }
  }

  // team t's tile p lives at image tile index t*16 + p (64-kv tiles).
  auto prefetch = [&](int p, int bi) {
    const int j = team * NPER + p;
    const _Float16* ks = Kb + j * 4096 + ttid * 8;
    const _Float16* vs = Vb + j * 4096 + ttid * 8;
    _Float16* kd = &kls[team][bi][ttid * 8];
    _Float16* vd = &vls[team][bi][ttid * 8];
    GLDS16(ks,        kd);
    GLDS16(ks + 2048, kd + 2048);
    GLDS16(vs,        vd);
    GLDS16(vs + 2048, vd + 2048);
    if (ttid < 16)
      GLDS16(Mb + team * 1024 + p * 64 + ttid * 4, &mls[team][bi][ttid * 4]);
  };

  f32x4 xacc[2][4];
#pragma unroll
  for (int u = 0; u < 2; ++u)
#pragma unroll
    for (int m = 0; m < 4; ++m) xacc[u][m] = (f32x4){0.f, 0.f, 0.f, 0.f};
  float lsum[2] = {0.0f, 0.0f};
  const hf16x2 one2 = {(__fp16)1.0f, (__fp16)1.0f};

  prefetch(0, 0);
  __syncthreads();

  for (int p = 0; p < NPER; ++p) {
    const int cur = p & 1;
    if (p + 1 < NPER) prefetch(p + 1, cur ^ 1);

    // S^T: A = K rows (rotated chunks), B = Q frags; K loads shared u=0,1.
    const _Float16* k0 = &kls[team][cur][x * 64 + ((quad + x) & 7) * 8];
    const _Float16* k1 = &kls[team][cur][x * 64 + ((quad + 4 + x) & 7) * 8];
    const float*    mp = &mls[team][cur][quad * 4];
    f16x4 pf[2][4];
#pragma unroll
    for (int t = 0; t < 4; ++t) {
      f16x8 ka0 = *(const f16x8*)(k0 + t * 1024);
      f16x8 ka1 = *(const f16x8*)(k1 + t * 1024);
      f32x4 mi = *(const f32x4*)(mp + t * 16);   // LDS broadcast read
#pragma unroll
      for (int u = 0; u < 2; ++u) {
        f32x4 st = __builtin_amdgcn_mfma_f32_16x16x32_f16(ka0, qf[u][0], mi, 0, 0, 0);
        st = __builtin_amdgcn_mfma_f32_16x16x32_f16(ka1, qf[u][1], st, 0, 0, 0);
        hf16x2 h0 = pkh(exp2_fast(st.x), exp2_fast(st.y));
        hf16x2 h1 = pkh(exp2_fast(st.z), exp2_fast(st.w));
#if __has_builtin(__builtin_amdgcn_fdot2)
        lsum[u] = __builtin_amdgcn_fdot2(h0, one2, lsum[u], false);
        lsum[u] = __builtin_amdgcn_fdot2(h1, one2, lsum[u], false);
#else
        f16x2 a0 = h2f(h0), a1 = h2f(h1);
        lsum[u] += (float)a0.x + (float)a0.y + (float)a1.x + (float)a1.y;
#endif
        union { f16x2 h[2]; f16x4 v; } r;
        r.h[0] = h2f(h0);
        r.h[1] = h2f(h1);
        pf[u][t] = r.v;
      }
    }
    // X^T += V^T P^T. V granule (d=16m+x, g=4t+quad) at slot g*64+d;
    // each vf reused for both q-strips.
    const _Float16* vbase = &vls[team][cur][256 * quad + 4 * x];
#pragma unroll
    for (int m = 0; m < 4; ++m) {
      f32x4 x0 = xacc[0][m];
      f32x4 x1 = xacc[1][m];
#pragma unroll
      for (int t = 0; t < 4; ++t) {
        f16x4 vf = *(const f16x4*)(vbase + 1024 * t + 64 * m);
        x0 = __builtin_amdgcn_mfma_f32_16x16x16f16(vf, pf[0][t], x0, 0, 0, 0);
        x1 = __builtin_amdgcn_mfma_f32_16x16x16f16(vf, pf[1][t], x1, 0, 0, 0);
      }
      xacc[0][m] = x0;
      xacc[1][m] = x1;
    }
    __syncthreads();
  }

  // quad-reduce l (same q = x across quads); both teams.
#pragma unroll
  for (int u = 0; u < 2; ++u) {
    lsum[u] += __shfl_xor(lsum[u], 16, 64);
    lsum[u] += __shfl_xor(lsum[u], 32, 64);
  }

  // ---- merge team 1's partials into team 0 via LDS (conflict-free:
  // region-major layout, each thread writes 16 B at stride 16 B).
  float* sx = (float*)&kls[0][0][0];   // 32 KB: 8 regions x 1024 floats
  float* sl = (float*)&vls[0][0][0];   // 2 KB
  if (team == 1) {
#pragma unroll
    for (int u = 0; u < 2; ++u) {
#pragma unroll
      for (int m = 0; m < 4; ++m)
        *(f32x4*)&sx[(u * 4 + m) * 1024 + ttid * 4] = xacc[u][m];
      sl[ttid * 2 + u] = lsum[u];
    }
  }
  __syncthreads();
  if (team == 0) {
#pragma unroll
    for (int u = 0; u < 2; ++u) {
      const float l = lsum[u] + sl[ttid * 2 + u];
      const float rl = 1.0f / l;
      float* op = Ob + (size_t)(q0 + u * 64) * DHEAD;
#pragma unroll
      for (int m = 0; m < 4; ++m) {
        f32x4 xo = xacc[u][m];
        f32x4 xr = *(const f32x4*)&sx[(u * 4 + m) * 1024 + ttid * 4];
        float4 o;
        o.x = (xo.x + xr.x) * rl;
        o.y = (xo.y + xr.y) * rl;
        o.z = (xo.z + xr.z) * rl;
        o.w = (xo.w + xr.w) * rl;
        *(float4*)(op + m * 16 + quad * 4) = o;
      }
    }
  }
}

extern "C" void kernel_launch(void* const* d_in, const int* in_sizes, int n_in,
                              void* d_out, int out_size, void* d_ws, size_t ws_size,
                              hipStream_t stream) {
  const float* Q = (const float*)d_in[0];
  const float* K = (const float*)d_in[1];
  const float* V = (const float*)d_in[2];
  const float* M = (const float*)d_in[3];
  float* O = (float*)d_out;

  _Float16* Kswz = (_Float16*)d_ws;
  _Float16* Vg   = Kswz + 4194304;                       // +8 MB
  float*    madd = (float*)((char*)d_ws + 16777216);     // +16 MB
  hipLaunchKernelGGL(prep, dim3(6144), dim3(256), 0, stream, K, V, M, Kswz, Vg, madd);
  hipLaunchKernelGGL(attn_ws, dim3(512), dim3(512), 0, stream, Q, Kswz, Vg, madd, O);
}